// Round 6
// baseline (135.271 us; speedup 1.0000x reference)
//
#include <hip/hip_runtime.h>
#include <hip/hip_bf16.h>
#include <cstdint>

#define Hh 16
#define Dd 1024
#define HD 64
#define Bb 2
#define Ss 2048

typedef float f32x4 __attribute__((ext_vector_type(4)));
typedef __bf16 bf16x8 __attribute__((ext_vector_type(8)));

__device__ __forceinline__ unsigned short f2bf(float f) {
  union { float f; unsigned u; } v; v.f = f;
  unsigned r = (v.u + 0x7FFFu + ((v.u >> 16) & 1u)) >> 16;  // RNE, finite inputs
  return (unsigned short)r;
}

__device__ __forceinline__ void gld16(const void* g, void* l) {
  __builtin_amdgcn_global_load_lds(
      (__attribute__((address_space(1))) void*)(g),
      (__attribute__((address_space(3))) void*)(l),
      16, 0, 0);
}

// ---------------------------------------------------------------------------
// Pack x (fp32 -> bf16), vectorized float4 -> ushort4
// ---------------------------------------------------------------------------
__global__ __launch_bounds__(256)
void pack_x_k(const float4* __restrict__ x, unsigned short* __restrict__ xb, int n4) {
  const int i = blockIdx.x * blockDim.x + threadIdx.x;
  if (i >= n4) return;
  const float4 v = x[i];
  ushort4 o;
  o.x = f2bf(v.x); o.y = f2bf(v.y); o.z = f2bf(v.z); o.w = f2bf(v.w);
  *(ushort4*)&xb[(size_t)i * 4] = o;
}

// ---------------------------------------------------------------------------
// Batched transpose + scale + fp32->bf16: out[m][c][r] = in[m][r][c] * scale
// grid: (C/64, R/64, nmat), block 256
// ---------------------------------------------------------------------------
__global__ __launch_bounds__(256)
void tconv_k(const float* __restrict__ in, unsigned short* __restrict__ out,
             int R, int C, float scale) {
  __shared__ float T[64][65];
  const int m = blockIdx.z;
  const float* src = in + (size_t)m * R * C;
  unsigned short* dst = out + (size_t)m * R * C;
  const int c0 = blockIdx.x * 64, r0 = blockIdx.y * 64;
  const int tx = threadIdx.x & 63, ty = threadIdx.x >> 6;
#pragma unroll
  for (int it = 0; it < 16; ++it) {
    const int i = ty + it * 4;
    T[i][tx] = src[(size_t)(r0 + i) * C + c0 + tx];
  }
  __syncthreads();
#pragma unroll
  for (int it = 0; it < 16; ++it) {
    const int jj = ty + it * 4;
    dst[(size_t)(c0 + jj) * R + r0 + tx] = f2bf(T[tx][jj] * scale);
  }
}

// ---------------------------------------------------------------------------
// bf16 GEMM, 128x128 tile, BK=64, 4 waves, 2-phase double-buffered LDS
// (prefetch next K-tile before compute, one barrier/step), T2 XOR-swizzle
// (pre-swizzled global source col + swizzled ds_read), 16x16x32 MFMA.
// EPI 0: q/k — TRANSPOSED acc (mfma operand swap) -> ushort4 scatter [bh][s][e]
// EPI 1: v   — normal acc -> ushort4 V^T [bh][e][s]
// EPI 2: out-proj — TRANSPOSED acc -> float4 +bias, row-major [m][n]
// ---------------------------------------------------------------------------
template <int EPI>
__global__ __launch_bounds__(256)
void gemm_bt(const unsigned short* __restrict__ A,
             const unsigned short* __restrict__ Bt,
             int K, int Ndim,
             unsigned short* __restrict__ q_out,
             unsigned short* __restrict__ k_out,
             unsigned short* __restrict__ vt_out,
             float* __restrict__ o_out,
             const float* __restrict__ bias)
{
  __shared__ unsigned short As[2][128 * 64];
  __shared__ unsigned short Bs[2][128 * 64];

  const int tid = threadIdx.x;
  const int w = tid >> 6, lane = tid & 63;
  const int lo = lane & 15, hi = lane >> 4;
  const int wr = w >> 1, wc = w & 1;
  const int row0 = blockIdx.y * 128;
  const int col0 = blockIdx.x * 128;

  f32x4 acc[4][4] = {};

  const int srow = w * 32 + (lane >> 3);            // staging row (+ c*8)
  const int scol = ((lane & 7) ^ (lane >> 3)) * 8;  // pre-swizzled source col
  const int swl  = (lo & 7) << 4;                   // read-side XOR

#define GSTAGE(bi, k0)                                                    \
  _Pragma("unroll")                                                       \
  for (int c = 0; c < 4; ++c) {                                           \
    const int rr = srow + c * 8;                                          \
    gld16(A  + (size_t)(row0 + rr) * K + ((k0) + scol),                   \
          (char*)&As[bi][0] + (w * 4 + c) * 1024);                        \
    gld16(Bt + (size_t)(col0 + rr) * K + ((k0) + scol),                   \
          (char*)&Bs[bi][0] + (w * 4 + c) * 1024);                        \
  }

  GSTAGE(0, 0);
  __syncthreads();

  const int nst = K >> 6;
  int cur = 0;
  for (int t = 0; t < nst; ++t) {
    if (t + 1 < nst) { GSTAGE(cur ^ 1, (t + 1) * 64); }
#pragma unroll
    for (int ks = 0; ks < 2; ++ks) {
      bf16x8 af[4], bfr[4];
#pragma unroll
      for (int i = 0; i < 4; ++i)
        af[i] = *(const bf16x8*)((const char*)&As[cur][0] +
                 (wr * 64 + i * 16 + lo) * 128 + ((ks * 64 + hi * 16) ^ swl));
#pragma unroll
      for (int j = 0; j < 4; ++j)
        bfr[j] = *(const bf16x8*)((const char*)&Bs[cur][0] +
                 (wc * 64 + j * 16 + lo) * 128 + ((ks * 64 + hi * 16) ^ swl));
      __builtin_amdgcn_s_setprio(1);
#pragma unroll
      for (int i = 0; i < 4; ++i)
#pragma unroll
        for (int j = 0; j < 4; ++j) {
          if (EPI == 1)
            acc[i][j] = __builtin_amdgcn_mfma_f32_16x16x32_bf16(af[i], bfr[j], acc[i][j], 0, 0, 0);
          else  // transposed output: D^T (rows = n)
            acc[i][j] = __builtin_amdgcn_mfma_f32_16x16x32_bf16(bfr[j], af[i], acc[i][j], 0, 0, 0);
        }
      __builtin_amdgcn_s_setprio(0);
    }
    __syncthreads();
    cur ^= 1;
  }

#pragma unroll
  for (int i = 0; i < 4; ++i) {
#pragma unroll
    for (int j = 0; j < 4; ++j) {
      if (EPI == 1) {
        // normal acc: lane holds 4 consecutive s at fixed e (V^T friendly)
        const int grow = row0 + wr * 64 + i * 16 + hi * 4;   // s (+r)
        const int gcol = col0 + wc * 64 + j * 16 + lo;       // 0..1023 in v
        const int hd = gcol >> 6, e = gcol & 63;
        const int bb2 = grow >> 11, s = grow & 2047;
        ushort4 pk;
        pk.x = f2bf(acc[i][j][0]); pk.y = f2bf(acc[i][j][1]);
        pk.z = f2bf(acc[i][j][2]); pk.w = f2bf(acc[i][j][3]);
        *(ushort4*)&vt_out[((size_t)(bb2 * Hh + hd) * HD + e) * Ss + s] = pk;
      } else {
        // transposed acc: lane holds 4 consecutive n at fixed row m
        const int m  = row0 + wr * 64 + i * 16 + lo;
        const int n0 = col0 + wc * 64 + j * 16 + hi * 4;
        if (EPI == 0) {
          const int p = n0 >> 10;
          const int hd = (n0 >> 6) & 15;
          const int e = n0 & 63;
          const int bb2 = m >> 11, s = m & 2047;
          unsigned short* dst = (p == 0) ? q_out : k_out;
          ushort4 pk;
          pk.x = f2bf(acc[i][j][0]); pk.y = f2bf(acc[i][j][1]);
          pk.z = f2bf(acc[i][j][2]); pk.w = f2bf(acc[i][j][3]);
          *(ushort4*)&dst[((size_t)(bb2 * Hh + hd) * Ss + s) * HD + e] = pk;
        } else {
          const float4 bv = *(const float4*)&bias[n0];
          float4 o;
          o.x = acc[i][j][0] + bv.x; o.y = acc[i][j][1] + bv.y;
          o.z = acc[i][j][2] + bv.z; o.w = acc[i][j][3] + bv.w;
          *(float4*)&o_out[(size_t)m * Ndim + n0] = o;
        }
      }
    }
  }
#undef GSTAGE
}

// ---------------------------------------------------------------------------
// Flash attention, causal, swapped-QK^T in-register-P version.
// grid (B*H, S/64 reversed heavy-first), 128 thr (2 waves x 32 q-rows).
// K rows staged through bit-perm perm(p)={p5,p3,p2,p4,p1,p0} so the swapped
// MFMA output (lane holds q=lane&15, kv slices in regs) is EXACTLY PV's
// A-fragment order: P = exp2(sacc - m) stays in registers, no LDS roundtrip.
// kf/vf reads amortized over 32 q-rows/wave. Defer-max lane-local common
// path; rare rescale via xor16/32 shfl + 16-lane redistribute. Row sums via
// MFMA-with-ones (lands in oacc domain). Scores in log2 domain (scale in Wq).
// ---------------------------------------------------------------------------
__global__ __launch_bounds__(128)
void attn_fwd(const unsigned short* __restrict__ qb,
              const unsigned short* __restrict__ kb,
              const unsigned short* __restrict__ vtb,
              unsigned short* __restrict__ ob)
{
  __shared__ unsigned short Ks[2][64 * 64];
  __shared__ unsigned short Vs[2][64 * 64];

  const int qt = 31 - blockIdx.y;        // heavy-first dispatch
  const int bh = blockIdx.x;
  const int bb2 = bh >> 4;
  const int hd = bh & 15;

  const unsigned short* Q  = qb  + (size_t)bh * Ss * HD;
  const unsigned short* Kg = kb  + (size_t)bh * Ss * HD;
  const unsigned short* Vt = vtb + (size_t)bh * HD * Ss;

  const int tid = threadIdx.x;
  const int w = tid >> 6, lane = tid & 63;
  const int lo = lane & 15, hi = lane >> 4;
  const int qrow0 = qt * 64 + w * 32;

  // staging: LDS row p = L*8 + sr (L = c*2+w), 8 lanes per row.
  const int sr  = lane >> 3;
  const int scol = ((lane & 7) ^ sr) * 8;   // pre-swizzled source col (elems)
  // permuted K source row offset for chunk c: perm(L*8+sr)
  int prow[4];
#pragma unroll
  for (int c = 0; c < 4; ++c) {
    const int L = c * 2 + w;
    prow[c] = (L >> 2) * 32 + ((L & 1) * 2 + (sr >> 2)) * 8 + ((L >> 1) & 1) * 4 + (sr & 3);
  }

#define STAGE(bi, kv)                                                     \
  _Pragma("unroll")                                                       \
  for (int c = 0; c < 4; ++c) {                                           \
    const int L = c * 2 + w;                                              \
    gld16(Kg + (size_t)((kv) + prow[c]) * HD + scol,                      \
          (char*)&Ks[bi][0] + L * 1024);                                  \
    gld16(Vt + (size_t)(L * 8 + sr) * Ss + (kv) + scol,                   \
          (char*)&Vs[bi][0] + L * 1024);                                  \
  }

  const int swl = (lo & 7) << 4;   // read-side XOR

  bf16x8 vones;
#pragma unroll
  for (int j = 0; j < 8; ++j) vones[j] = (__bf16)1.0f;

  bf16x8 qf[2][2];
#pragma unroll
  for (int mi = 0; mi < 2; ++mi)
#pragma unroll
    for (int ks = 0; ks < 2; ++ks)
      qf[mi][ks] = *(const bf16x8*)&Q[(size_t)(qrow0 + mi * 16 + lo) * HD + ks * 32 + hi * 8];

  f32x4 oacc[2][4] = {};
  float m2s[2];                 // running max, sacc domain (q = ...+lo)
  float l2[2][4];               // running denom, oacc domain (q = ...+hi*4+r)
#pragma unroll
  for (int mi = 0; mi < 2; ++mi) {
    m2s[mi] = -INFINITY;
#pragma unroll
    for (int r = 0; r < 4; ++r) l2[mi][r] = 0.f;
  }

  const int ntiles = qt + 1;

  STAGE(0, 0);
  __syncthreads();

  int cur = 0;
  for (int t = 0; t < ntiles; ++t) {
    if (t + 1 < ntiles) { STAGE(cur ^ 1, (t + 1) * 64); }

    // S^T = K Q^T (swapped): lane holds q = qrow0+mi*16+lo,
    // reg (nj,r) holds kv = (nj>>1)*32 + hi*8 + (nj&1)*4 + r  (via perm)
    f32x4 sacc[2][4] = {};
    __builtin_amdgcn_s_setprio(1);
#pragma unroll
    for (int ks = 0; ks < 2; ++ks) {
      bf16x8 kf[4];
#pragma unroll
      for (int nj = 0; nj < 4; ++nj)
        kf[nj] = *(const bf16x8*)((const char*)&Ks[cur][0] +
                 (nj * 16 + lo) * 128 + ((ks * 64 + hi * 16) ^ swl));
#pragma unroll
      for (int mi = 0; mi < 2; ++mi)
#pragma unroll
        for (int nj = 0; nj < 4; ++nj)
          sacc[mi][nj] = __builtin_amdgcn_mfma_f32_16x16x32_bf16(kf[nj], qf[mi][ks], sacc[mi][nj], 0, 0, 0);
    }
    __builtin_amdgcn_s_setprio(0);

    // causal mask (diagonal tile only)
    if (t == qt) {
#pragma unroll
      for (int mi = 0; mi < 2; ++mi) {
        const int qr = w * 32 + mi * 16 + lo;
#pragma unroll
        for (int nj = 0; nj < 4; ++nj) {
          const int kb0 = (nj >> 1) * 32 + (nj & 1) * 4 + hi * 8;
#pragma unroll
          for (int r = 0; r < 4; ++r)
            if (kb0 + r > qr) sacc[mi][nj][r] = -INFINITY;
        }
      }
    }

    // lane-local max + defer-max test (no cross-lane in common path)
    float lmax[2];
#pragma unroll
    for (int mi = 0; mi < 2; ++mi) {
      float a = fmaxf(fmaxf(sacc[mi][0][0], sacc[mi][0][1]),
                      fmaxf(sacc[mi][0][2], sacc[mi][0][3]));
      float b = fmaxf(fmaxf(sacc[mi][1][0], sacc[mi][1][1]),
                      fmaxf(sacc[mi][1][2], sacc[mi][1][3]));
      float c = fmaxf(fmaxf(sacc[mi][2][0], sacc[mi][2][1]),
                      fmaxf(sacc[mi][2][2], sacc[mi][2][3]));
      float d = fmaxf(fmaxf(sacc[mi][3][0], sacc[mi][3][1]),
                      fmaxf(sacc[mi][3][2], sacc[mi][3][3]));
      lmax[mi] = fmaxf(fmaxf(a, b), fmaxf(c, d));
    }
    const float dmax = fmaxf(lmax[0] - m2s[0], lmax[1] - m2s[1]);
    if (!__all(dmax <= 8.0f)) {
      float rcs[2];
#pragma unroll
      for (int mi = 0; mi < 2; ++mi) {
        float rm = lmax[mi];
        rm = fmaxf(rm, __shfl_xor(rm, 16, 64));
        rm = fmaxf(rm, __shfl_xor(rm, 32, 64));
        const float mn = fmaxf(m2s[mi], rm);
        rcs[mi] = __builtin_amdgcn_exp2f(m2s[mi] - mn);
        m2s[mi] = mn;
      }
#pragma unroll
      for (int mi = 0; mi < 2; ++mi)
#pragma unroll
        for (int r = 0; r < 4; ++r) {
          const float rc = __shfl(rcs[mi], hi * 4 + r, 64);
          l2[mi][r] *= rc;
#pragma unroll
          for (int nj = 0; nj < 4; ++nj)
            oacc[mi][nj][r] *= rc;
        }
    }

    // P = exp2(S - m) packed straight into PV A-fragments (in registers)
    bf16x8 pa[2][2];
#pragma unroll
    for (int mi = 0; mi < 2; ++mi)
#pragma unroll
      for (int ks = 0; ks < 2; ++ks)
#pragma unroll
        for (int j = 0; j < 4; ++j) {
          pa[mi][ks][j]     = (__bf16)__builtin_amdgcn_exp2f(sacc[mi][2 * ks][j]     - m2s[mi]);
          pa[mi][ks][4 + j] = (__bf16)__builtin_amdgcn_exp2f(sacc[mi][2 * ks + 1][j] - m2s[mi]);
        }

    // O += P V ; row sums via MFMA-with-ones
    f32x4 osum[2] = {};
    __builtin_amdgcn_s_setprio(1);
#pragma unroll
    for (int ks = 0; ks < 2; ++ks) {
      bf16x8 vf[4];
#pragma unroll
      for (int nj = 0; nj < 4; ++nj)
        vf[nj] = *(const bf16x8*)((const char*)&Vs[cur][0] +
                 (nj * 16 + lo) * 128 + ((ks * 64 + hi * 16) ^ swl));
#pragma unroll
      for (int mi = 0; mi < 2; ++mi) {
#pragma unroll
        for (int nj = 0; nj < 4; ++nj)
          oacc[mi][nj] = __builtin_amdgcn_mfma_f32_16x16x32_bf16(pa[mi][ks], vf[nj], oacc[mi][nj], 0, 0, 0);
        osum[mi] = __builtin_amdgcn_mfma_f32_16x16x32_bf16(pa[mi][ks], vones, osum[mi], 0, 0, 0);
      }
    }
    __builtin_amdgcn_s_setprio(0);
#pragma unroll
    for (int mi = 0; mi < 2; ++mi)
#pragma unroll
      for (int r = 0; r < 4; ++r)
        l2[mi][r] += osum[mi][r];

    __syncthreads();
    cur ^= 1;
  }
#undef STAGE

  // epilogue: ob[b][s][h*64+e] bf16
#pragma unroll
  for (int mi = 0; mi < 2; ++mi) {
#pragma unroll
    for (int r = 0; r < 4; ++r) {
      const int s = qrow0 + mi * 16 + hi * 4 + r;
      const float il = 1.0f / l2[mi][r];
      const size_t base = ((size_t)bb2 * Ss + s) * Dd + hd * HD;
#pragma unroll
      for (int nj = 0; nj < 4; ++nj)
        ob[base + nj * 16 + lo] = f2bf(oacc[mi][nj][r] * il);
    }
  }
}

// ---------------------------------------------------------------------------
extern "C" void kernel_launch(void* const* d_in, const int* in_sizes, int n_in,
                              void* d_out, int out_size, void* d_ws, size_t ws_size,
                              hipStream_t stream)
{
  const float* x  = (const float*)d_in[0];
  const float* Wq = (const float*)d_in[1];
  const float* Wk = (const float*)d_in[2];
  const float* Wv = (const float*)d_in[3];
  const float* Wo = (const float*)d_in[4];
  const float* bo = (const float*)d_in[5];
  float* out = (float*)d_out;

  char* ws = (char*)d_ws;
  unsigned short* xb    = (unsigned short*)(ws);              //  8,388,608 B
  unsigned short* wqkvT = (unsigned short*)(ws + 8388608);    //  6,291,456 B
  unsigned short* woT   = (unsigned short*)(ws + 14680064);   //  2,097,152 B
  unsigned short* qb    = (unsigned short*)(ws + 16777216);   //  8,388,608 B
  unsigned short* kb    = (unsigned short*)(ws + 25165824);   //  8,388,608 B
  unsigned short* vtb   = (unsigned short*)(ws + 33554432);   //  8,388,608 B
  unsigned short* ob    = (unsigned short*)(ws + 41943040);   //  8,388,608 B (end 48 MiB)

  pack_x_k<<<4096, 256, 0, stream>>>((const float4*)x, xb, 1048576);
  // Wq carries 1/sqrt(HD) * log2(e) so attention scores land in log2 domain
  tconv_k<<<dim3(1, 16, 16), 256, 0, stream>>>(Wq, wqkvT,           1024, 64, 0.18033688011112042f);
  tconv_k<<<dim3(1, 16, 16), 256, 0, stream>>>(Wk, wqkvT + 1048576, 1024, 64, 1.0f);
  tconv_k<<<dim3(1, 16, 16), 256, 0, stream>>>(Wv, wqkvT + 2097152, 1024, 64, 1.0f);
  tconv_k<<<dim3(16, 16, 1), 256, 0, stream>>>(Wo, woT,             1024, 1024, 1.0f);

  // q/k projection: [4096x1024] @ [1024x2048] (transposed-output epilogue)
  gemm_bt<0><<<dim3(16, 32), 256, 0, stream>>>(xb, wqkvT, 1024, 0,
                                               qb, kb, nullptr, nullptr, nullptr);
  // v projection: [4096x1024] @ [1024x1024] -> V^T
  gemm_bt<1><<<dim3(8, 32), 256, 0, stream>>>(xb, wqkvT + 2097152, 1024, 0,
                                              nullptr, nullptr, vtb, nullptr, nullptr);
  // attention (2 waves x 32 q-rows per 64-row q-tile; in-register P)
  attn_fwd<<<dim3(32, 32), 128, 0, stream>>>(qb, kb, vtb, ob);
  // out-proj: [4096x1024] @ [1024x1024] + bo (transposed-output epilogue)
  gemm_bt<2><<<dim3(8, 32), 256, 0, stream>>>(ob, woT, 1024, 1024,
                                              nullptr, nullptr, nullptr, out, bo);
}

// Round 7
// 131.768 us; speedup vs baseline: 1.0266x; 1.0266x over previous
//
#include <hip/hip_runtime.h>
#include <hip/hip_bf16.h>
#include <cstdint>

#define Hh 16
#define Dd 1024
#define HD 64
#define Bb 2
#define Ss 2048

typedef float f32x4 __attribute__((ext_vector_type(4)));
typedef __bf16 bf16x8 __attribute__((ext_vector_type(8)));

__device__ __forceinline__ unsigned short f2bf(float f) {
  union { float f; unsigned u; } v; v.f = f;
  unsigned r = (v.u + 0x7FFFu + ((v.u >> 16) & 1u)) >> 16;  // RNE, finite inputs
  return (unsigned short)r;
}

__device__ __forceinline__ void gld16(const void* g, void* l) {
  __builtin_amdgcn_global_load_lds(
      (__attribute__((address_space(1))) void*)(g),
      (__attribute__((address_space(3))) void*)(l),
      16, 0, 0);
}

// ---------------------------------------------------------------------------
// Pack x (fp32 -> bf16), vectorized float4 -> ushort4
// ---------------------------------------------------------------------------
__global__ __launch_bounds__(256)
void pack_x_k(const float4* __restrict__ x, unsigned short* __restrict__ xb, int n4) {
  const int i = blockIdx.x * blockDim.x + threadIdx.x;
  if (i >= n4) return;
  const float4 v = x[i];
  ushort4 o;
  o.x = f2bf(v.x); o.y = f2bf(v.y); o.z = f2bf(v.z); o.w = f2bf(v.w);
  *(ushort4*)&xb[(size_t)i * 4] = o;
}

// ---------------------------------------------------------------------------
// Batched transpose + scale + fp32->bf16: out[m][c][r] = in[m][r][c] * scale
// grid: (C/64, R/64, nmat), block 256
// ---------------------------------------------------------------------------
__global__ __launch_bounds__(256)
void tconv_k(const float* __restrict__ in, unsigned short* __restrict__ out,
             int R, int C, float scale) {
  __shared__ float T[64][65];
  const int m = blockIdx.z;
  const float* src = in + (size_t)m * R * C;
  unsigned short* dst = out + (size_t)m * R * C;
  const int c0 = blockIdx.x * 64, r0 = blockIdx.y * 64;
  const int tx = threadIdx.x & 63, ty = threadIdx.x >> 6;
#pragma unroll
  for (int it = 0; it < 16; ++it) {
    const int i = ty + it * 4;
    T[i][tx] = src[(size_t)(r0 + i) * C + c0 + tx];
  }
  __syncthreads();
#pragma unroll
  for (int it = 0; it < 16; ++it) {
    const int jj = ty + it * 4;
    dst[(size_t)(c0 + jj) * R + r0 + tx] = f2bf(T[tx][jj] * scale);
  }
}

// ---------------------------------------------------------------------------
// Merged QKV projection: A[4096][1024] @ wqkvT[3072][1024]^T.
// 128x128 tile, BK=64, 4 waves, 2-phase double-buffered LDS, T2 XOR-swizzle.
// Per-block uniform branch: col0 < 2048 -> q/k (TRANSPOSED acc via operand
// swap, ushort4 scatter [bh][s][e]); else v (normal acc, ushort4 V^T).
// ---------------------------------------------------------------------------
__global__ __launch_bounds__(256)
void gemm_qkv(const unsigned short* __restrict__ A,
              const unsigned short* __restrict__ Bt,
              unsigned short* __restrict__ q_out,
              unsigned short* __restrict__ k_out,
              unsigned short* __restrict__ vt_out)
{
  __shared__ unsigned short As[2][128 * 64];
  __shared__ unsigned short Bs[2][128 * 64];

  const int K = 1024;
  const int tid = threadIdx.x;
  const int w = tid >> 6, lane = tid & 63;
  const int lo = lane & 15, hi = lane >> 4;
  const int wr = w >> 1, wc = w & 1;
  const int row0 = blockIdx.y * 128;
  const int col0 = blockIdx.x * 128;
  const bool isv = (col0 >= 2048);

  f32x4 acc[4][4] = {};

  const int srow = w * 32 + (lane >> 3);
  const int scol = ((lane & 7) ^ (lane >> 3)) * 8;
  const int swl  = (lo & 7) << 4;

#define GSTAGE(bi, k0)                                                    \
  _Pragma("unroll")                                                       \
  for (int c = 0; c < 4; ++c) {                                           \
    const int rr = srow + c * 8;                                          \
    gld16(A  + (size_t)(row0 + rr) * K + ((k0) + scol),                   \
          (char*)&As[bi][0] + (w * 4 + c) * 1024);                        \
    gld16(Bt + (size_t)(col0 + rr) * K + ((k0) + scol),                   \
          (char*)&Bs[bi][0] + (w * 4 + c) * 1024);                        \
  }

  GSTAGE(0, 0);
  __syncthreads();

  int cur = 0;
  for (int t = 0; t < 16; ++t) {
    if (t + 1 < 16) { GSTAGE(cur ^ 1, (t + 1) * 64); }
#pragma unroll
    for (int ks = 0; ks < 2; ++ks) {
      bf16x8 af[4], bfr[4];
#pragma unroll
      for (int i = 0; i < 4; ++i)
        af[i] = *(const bf16x8*)((const char*)&As[cur][0] +
                 (wr * 64 + i * 16 + lo) * 128 + ((ks * 64 + hi * 16) ^ swl));
#pragma unroll
      for (int j = 0; j < 4; ++j)
        bfr[j] = *(const bf16x8*)((const char*)&Bs[cur][0] +
                 (wc * 64 + j * 16 + lo) * 128 + ((ks * 64 + hi * 16) ^ swl));
      __builtin_amdgcn_s_setprio(1);
      if (isv) {
#pragma unroll
        for (int i = 0; i < 4; ++i)
#pragma unroll
          for (int j = 0; j < 4; ++j)
            acc[i][j] = __builtin_amdgcn_mfma_f32_16x16x32_bf16(af[i], bfr[j], acc[i][j], 0, 0, 0);
      } else {
#pragma unroll
        for (int i = 0; i < 4; ++i)
#pragma unroll
          for (int j = 0; j < 4; ++j)
            acc[i][j] = __builtin_amdgcn_mfma_f32_16x16x32_bf16(bfr[j], af[i], acc[i][j], 0, 0, 0);
      }
      __builtin_amdgcn_s_setprio(0);
    }
    __syncthreads();
    cur ^= 1;
  }

#pragma unroll
  for (int i = 0; i < 4; ++i) {
#pragma unroll
    for (int j = 0; j < 4; ++j) {
      if (isv) {
        // normal acc: lane holds 4 consecutive s at fixed e
        const int grow = row0 + wr * 64 + i * 16 + hi * 4;
        const int gcol = col0 + wc * 64 + j * 16 + lo;     // 2048..3071
        const int hd = (gcol >> 6) & 15, e = gcol & 63;
        const int bb2 = grow >> 11, s = grow & 2047;
        ushort4 pk;
        pk.x = f2bf(acc[i][j][0]); pk.y = f2bf(acc[i][j][1]);
        pk.z = f2bf(acc[i][j][2]); pk.w = f2bf(acc[i][j][3]);
        *(ushort4*)&vt_out[((size_t)(bb2 * Hh + hd) * HD + e) * Ss + s] = pk;
      } else {
        // transposed acc: lane holds 4 consecutive n at fixed row m
        const int m  = row0 + wr * 64 + i * 16 + lo;
        const int n0 = col0 + wc * 64 + j * 16 + hi * 4;
        const int p = n0 >> 10;
        const int hd = (n0 >> 6) & 15, e = n0 & 63;
        const int bb2 = m >> 11, s = m & 2047;
        unsigned short* dst = (p == 0) ? q_out : k_out;
        ushort4 pk;
        pk.x = f2bf(acc[i][j][0]); pk.y = f2bf(acc[i][j][1]);
        pk.z = f2bf(acc[i][j][2]); pk.w = f2bf(acc[i][j][3]);
        *(ushort4*)&dst[((size_t)(bb2 * Hh + hd) * Ss + s) * HD + e] = pk;
      }
    }
  }
#undef GSTAGE
}

// ---------------------------------------------------------------------------
// Out-projection GEMM: [4096x1024] @ woT[1024][1024]^T + bias, fp32 out.
// Same 2-phase structure; TRANSPOSED acc -> float4 stores.
// ---------------------------------------------------------------------------
__global__ __launch_bounds__(256)
void gemm_out(const unsigned short* __restrict__ A,
              const unsigned short* __restrict__ Bt,
              float* __restrict__ o_out,
              const float* __restrict__ bias)
{
  __shared__ unsigned short As[2][128 * 64];
  __shared__ unsigned short Bs[2][128 * 64];

  const int K = 1024, Ndim = 1024;
  const int tid = threadIdx.x;
  const int w = tid >> 6, lane = tid & 63;
  const int lo = lane & 15, hi = lane >> 4;
  const int wr = w >> 1, wc = w & 1;
  const int row0 = blockIdx.y * 128;
  const int col0 = blockIdx.x * 128;

  f32x4 acc[4][4] = {};

  const int srow = w * 32 + (lane >> 3);
  const int scol = ((lane & 7) ^ (lane >> 3)) * 8;
  const int swl  = (lo & 7) << 4;

#define GSTAGE(bi, k0)                                                    \
  _Pragma("unroll")                                                       \
  for (int c = 0; c < 4; ++c) {                                           \
    const int rr = srow + c * 8;                                          \
    gld16(A  + (size_t)(row0 + rr) * K + ((k0) + scol),                   \
          (char*)&As[bi][0] + (w * 4 + c) * 1024);                        \
    gld16(Bt + (size_t)(col0 + rr) * K + ((k0) + scol),                   \
          (char*)&Bs[bi][0] + (w * 4 + c) * 1024);                        \
  }

  GSTAGE(0, 0);
  __syncthreads();

  int cur = 0;
  for (int t = 0; t < 16; ++t) {
    if (t + 1 < 16) { GSTAGE(cur ^ 1, (t + 1) * 64); }
#pragma unroll
    for (int ks = 0; ks < 2; ++ks) {
      bf16x8 af[4], bfr[4];
#pragma unroll
      for (int i = 0; i < 4; ++i)
        af[i] = *(const bf16x8*)((const char*)&As[cur][0] +
                 (wr * 64 + i * 16 + lo) * 128 + ((ks * 64 + hi * 16) ^ swl));
#pragma unroll
      for (int j = 0; j < 4; ++j)
        bfr[j] = *(const bf16x8*)((const char*)&Bs[cur][0] +
                 (wc * 64 + j * 16 + lo) * 128 + ((ks * 64 + hi * 16) ^ swl));
      __builtin_amdgcn_s_setprio(1);
#pragma unroll
      for (int i = 0; i < 4; ++i)
#pragma unroll
        for (int j = 0; j < 4; ++j)
          acc[i][j] = __builtin_amdgcn_mfma_f32_16x16x32_bf16(bfr[j], af[i], acc[i][j], 0, 0, 0);
      __builtin_amdgcn_s_setprio(0);
    }
    __syncthreads();
    cur ^= 1;
  }

#pragma unroll
  for (int i = 0; i < 4; ++i) {
#pragma unroll
    for (int j = 0; j < 4; ++j) {
      const int m  = row0 + wr * 64 + i * 16 + lo;
      const int n0 = col0 + wc * 64 + j * 16 + hi * 4;
      const float4 bv = *(const float4*)&bias[n0];
      float4 o;
      o.x = acc[i][j][0] + bv.x; o.y = acc[i][j][1] + bv.y;
      o.z = acc[i][j][2] + bv.z; o.w = acc[i][j][3] + bv.w;
      *(float4*)&o_out[(size_t)m * Ndim + n0] = o;
    }
  }
#undef GSTAGE
}

// ---------------------------------------------------------------------------
// Flash attention, causal, swapped-QK^T in-register-P, 4 waves x 16 q-rows.
// grid (B*H, S/64 reversed heavy-first), 256 thr. K rows staged through
// bit-perm perm(p)={p5,p3,p2,p4,p1,p0} so the swapped MFMA output (lane holds
// q=lane&15, kv slices in regs) is EXACTLY PV's A-fragment order: P stays in
// registers. Defer-max lane-local common path; rare rescale via xor16/32
// shfl + 16-lane redistribute. Row sums via MFMA-with-ones. Scores in log2
// domain (scale folded into Wq).
// ---------------------------------------------------------------------------
__global__ __launch_bounds__(256)
void attn_fwd(const unsigned short* __restrict__ qb,
              const unsigned short* __restrict__ kb,
              const unsigned short* __restrict__ vtb,
              unsigned short* __restrict__ ob)
{
  __shared__ unsigned short Ks[2][64 * 64];
  __shared__ unsigned short Vs[2][64 * 64];

  const int qt = 31 - blockIdx.y;        // heavy-first dispatch
  const int bh = blockIdx.x;
  const int bb2 = bh >> 4;
  const int hd = bh & 15;

  const unsigned short* Q  = qb  + (size_t)bh * Ss * HD;
  const unsigned short* Kg = kb  + (size_t)bh * Ss * HD;
  const unsigned short* Vt = vtb + (size_t)bh * HD * Ss;

  const int tid = threadIdx.x;
  const int w = tid >> 6, lane = tid & 63;
  const int lo = lane & 15, hi = lane >> 4;
  const int qrow0 = qt * 64 + w * 16;

  // staging: LDS row p = L*8 + sr (L = c*4+w), 8 lanes per row.
  const int sr   = lane >> 3;
  const int scol = ((lane & 7) ^ sr) * 8;   // pre-swizzled source col (elems)
  int prow[2];
#pragma unroll
  for (int c = 0; c < 2; ++c) {
    const int L = c * 4 + w;
    prow[c] = (L >> 2) * 32 + ((L & 1) * 2 + (sr >> 2)) * 8 + ((L >> 1) & 1) * 4 + (sr & 3);
  }

#define STAGE(bi, kv)                                                     \
  _Pragma("unroll")                                                       \
  for (int c = 0; c < 2; ++c) {                                           \
    const int L = c * 4 + w;                                              \
    gld16(Kg + (size_t)((kv) + prow[c]) * HD + scol,                      \
          (char*)&Ks[bi][0] + L * 1024);                                  \
    gld16(Vt + (size_t)(L * 8 + sr) * Ss + (kv) + scol,                   \
          (char*)&Vs[bi][0] + L * 1024);                                  \
  }

  const int swl = (lo & 7) << 4;   // read-side XOR

  bf16x8 vones;
#pragma unroll
  for (int j = 0; j < 8; ++j) vones[j] = (__bf16)1.0f;

  bf16x8 qf[2];
#pragma unroll
  for (int ks = 0; ks < 2; ++ks)
    qf[ks] = *(const bf16x8*)&Q[(size_t)(qrow0 + lo) * HD + ks * 32 + hi * 8];

  f32x4 oacc[4] = {};
  float m2s = -INFINITY;   // running max, sacc domain (q = qrow0+lo)
  float l2[4];             // running denom, oacc domain (q = qrow0+hi*4+r)
#pragma unroll
  for (int r = 0; r < 4; ++r) l2[r] = 0.f;

  const int ntiles = qt + 1;

  STAGE(0, 0);
  __syncthreads();

  int cur = 0;
  for (int t = 0; t < ntiles; ++t) {
    if (t + 1 < ntiles) { STAGE(cur ^ 1, (t + 1) * 64); }

    // S^T = K Q^T (swapped): lane holds q = qrow0+lo,
    // reg (nj,r) holds kv = (nj>>1)*32 + (nj&1)*4 + hi*8 + r  (via perm)
    f32x4 sacc[4] = {};
    __builtin_amdgcn_s_setprio(1);
#pragma unroll
    for (int ks = 0; ks < 2; ++ks) {
      bf16x8 kf[4];
#pragma unroll
      for (int nj = 0; nj < 4; ++nj)
        kf[nj] = *(const bf16x8*)((const char*)&Ks[cur][0] +
                 (nj * 16 + lo) * 128 + ((ks * 64 + hi * 16) ^ swl));
#pragma unroll
      for (int nj = 0; nj < 4; ++nj)
        sacc[nj] = __builtin_amdgcn_mfma_f32_16x16x32_bf16(kf[nj], qf[ks], sacc[nj], 0, 0, 0);
    }
    __builtin_amdgcn_s_setprio(0);

    // causal mask (diagonal tile only); indices tile-local
    if (t == qt) {
      const int qr = w * 16 + lo;
#pragma unroll
      for (int nj = 0; nj < 4; ++nj) {
        const int kb0 = (nj >> 1) * 32 + (nj & 1) * 4 + hi * 8;
#pragma unroll
        for (int r = 0; r < 4; ++r)
          if (kb0 + r > qr) sacc[nj][r] = -INFINITY;
      }
    }

    // lane-local max + defer-max test (no cross-lane in common path)
    float a0 = fmaxf(fmaxf(sacc[0][0], sacc[0][1]), fmaxf(sacc[0][2], sacc[0][3]));
    float a1 = fmaxf(fmaxf(sacc[1][0], sacc[1][1]), fmaxf(sacc[1][2], sacc[1][3]));
    float a2 = fmaxf(fmaxf(sacc[2][0], sacc[2][1]), fmaxf(sacc[2][2], sacc[2][3]));
    float a3 = fmaxf(fmaxf(sacc[3][0], sacc[3][1]), fmaxf(sacc[3][2], sacc[3][3]));
    const float lmax = fmaxf(fmaxf(a0, a1), fmaxf(a2, a3));
    if (!__all(lmax - m2s <= 8.0f)) {
      float rm = lmax;
      rm = fmaxf(rm, __shfl_xor(rm, 16, 64));
      rm = fmaxf(rm, __shfl_xor(rm, 32, 64));
      const float mn = fmaxf(m2s, rm);
      const float rcs = __builtin_amdgcn_exp2f(m2s - mn);
      m2s = mn;
#pragma unroll
      for (int r = 0; r < 4; ++r) {
        const float rc = __shfl(rcs, hi * 4 + r, 64);
        l2[r] *= rc;
#pragma unroll
        for (int nj = 0; nj < 4; ++nj)
          oacc[nj][r] *= rc;
      }
    }

    // P = exp2(S - m) packed straight into PV A-fragments (in registers)
    bf16x8 pa[2];
#pragma unroll
    for (int ks = 0; ks < 2; ++ks)
#pragma unroll
      for (int j = 0; j < 4; ++j) {
        pa[ks][j]     = (__bf16)__builtin_amdgcn_exp2f(sacc[2 * ks][j]     - m2s);
        pa[ks][4 + j] = (__bf16)__builtin_amdgcn_exp2f(sacc[2 * ks + 1][j] - m2s);
      }

    // O += P V ; row sums via MFMA-with-ones
    f32x4 osum = {};
    __builtin_amdgcn_s_setprio(1);
#pragma unroll
    for (int ks = 0; ks < 2; ++ks) {
      bf16x8 vf[4];
#pragma unroll
      for (int nj = 0; nj < 4; ++nj)
        vf[nj] = *(const bf16x8*)((const char*)&Vs[cur][0] +
                 (nj * 16 + lo) * 128 + ((ks * 64 + hi * 16) ^ swl));
#pragma unroll
      for (int nj = 0; nj < 4; ++nj)
        oacc[nj] = __builtin_amdgcn_mfma_f32_16x16x32_bf16(pa[ks], vf[nj], oacc[nj], 0, 0, 0);
      osum = __builtin_amdgcn_mfma_f32_16x16x32_bf16(pa[ks], vones, osum, 0, 0, 0);
    }
    __builtin_amdgcn_s_setprio(0);
#pragma unroll
    for (int r = 0; r < 4; ++r)
      l2[r] += osum[r];

    __syncthreads();
    cur ^= 1;
  }
#undef STAGE

  // epilogue: ob[b][s][h*64+e] bf16
#pragma unroll
  for (int r = 0; r < 4; ++r) {
    const int s = qrow0 + hi * 4 + r;
    const float il = 1.0f / l2[r];
    const size_t base = ((size_t)bb2 * Ss + s) * Dd + hd * HD;
#pragma unroll
    for (int nj = 0; nj < 4; ++nj)
      ob[base + nj * 16 + lo] = f2bf(oacc[nj][r] * il);
  }
}

// ---------------------------------------------------------------------------
extern "C" void kernel_launch(void* const* d_in, const int* in_sizes, int n_in,
                              void* d_out, int out_size, void* d_ws, size_t ws_size,
                              hipStream_t stream)
{
  const float* x  = (const float*)d_in[0];
  const float* Wq = (const float*)d_in[1];
  const float* Wk = (const float*)d_in[2];
  const float* Wv = (const float*)d_in[3];
  const float* Wo = (const float*)d_in[4];
  const float* bo = (const float*)d_in[5];
  float* out = (float*)d_out;

  char* ws = (char*)d_ws;
  unsigned short* xb    = (unsigned short*)(ws);              //  8,388,608 B
  unsigned short* wqkvT = (unsigned short*)(ws + 8388608);    //  6,291,456 B
  unsigned short* woT   = (unsigned short*)(ws + 14680064);   //  2,097,152 B
  unsigned short* qb    = (unsigned short*)(ws + 16777216);   //  8,388,608 B
  unsigned short* kb    = (unsigned short*)(ws + 25165824);   //  8,388,608 B
  unsigned short* vtb   = (unsigned short*)(ws + 33554432);   //  8,388,608 B
  unsigned short* ob    = (unsigned short*)(ws + 41943040);   //  8,388,608 B (end 48 MiB)

  pack_x_k<<<4096, 256, 0, stream>>>((const float4*)x, xb, 1048576);
  // Wq carries 1/sqrt(HD) * log2(e) so attention scores land in log2 domain
  tconv_k<<<dim3(1, 16, 16), 256, 0, stream>>>(Wq, wqkvT,           1024, 64, 0.18033688011112042f);
  tconv_k<<<dim3(1, 16, 16), 256, 0, stream>>>(Wk, wqkvT + 1048576, 1024, 64, 1.0f);
  tconv_k<<<dim3(1, 16, 16), 256, 0, stream>>>(Wv, wqkvT + 2097152, 1024, 64, 1.0f);
  tconv_k<<<dim3(16, 16, 1), 256, 0, stream>>>(Wo, woT,             1024, 1024, 1.0f);

  // merged QKV projection: [4096x1024] @ [1024x3072]
  gemm_qkv<<<dim3(24, 32), 256, 0, stream>>>(xb, wqkvT, qb, kb, vtb);
  // attention (4 waves x 16 q-rows per 64-row q-tile; in-register P)
  attn_fwd<<<dim3(32, 32), 256, 0, stream>>>(qb, kb, vtb, ob);
  // out-proj: [4096x1024] @ [1024x1024] + bo (transposed-output epilogue)
  gemm_out<<<dim3(8, 32), 256, 0, stream>>>(ob, woT, out, bo);
}

// Round 8
// 124.354 us; speedup vs baseline: 1.0878x; 1.0596x over previous
//
#include <hip/hip_runtime.h>
#include <hip/hip_bf16.h>
#include <cstdint>

#define Hh 16
#define Dd 1024
#define HD 64
#define Bb 2
#define Ss 2048

typedef float f32x4 __attribute__((ext_vector_type(4)));
typedef __bf16 bf16x8 __attribute__((ext_vector_type(8)));

__device__ __forceinline__ unsigned short f2bf(float f) {
  union { float f; unsigned u; } v; v.f = f;
  unsigned r = (v.u + 0x7FFFu + ((v.u >> 16) & 1u)) >> 16;  // RNE, finite inputs
  return (unsigned short)r;
}

__device__ __forceinline__ void gld16(const void* g, void* l) {
  __builtin_amdgcn_global_load_lds(
      (__attribute__((address_space(1))) void*)(g),
      (__attribute__((address_space(3))) void*)(l),
      16, 0, 0);
}

// ---------------------------------------------------------------------------
// Pack x (fp32 -> bf16), vectorized float4 -> ushort4
// ---------------------------------------------------------------------------
__global__ __launch_bounds__(256)
void pack_x_k(const float4* __restrict__ x, unsigned short* __restrict__ xb, int n4) {
  const int i = blockIdx.x * blockDim.x + threadIdx.x;
  if (i >= n4) return;
  const float4 v = x[i];
  ushort4 o;
  o.x = f2bf(v.x); o.y = f2bf(v.y); o.z = f2bf(v.z); o.w = f2bf(v.w);
  *(ushort4*)&xb[(size_t)i * 4] = o;
}

// ---------------------------------------------------------------------------
// Merged Wq/Wk/Wv transpose + scale + fp32->bf16 (z = 0..47; 16 mats each)
// out[m][c][r] = in[m mod 16][r][c] * scale(m)
// ---------------------------------------------------------------------------
__global__ __launch_bounds__(256)
void tconv_qkv(const float* __restrict__ Wq, const float* __restrict__ Wk,
               const float* __restrict__ Wv, unsigned short* __restrict__ out,
               float qscale) {
  __shared__ float T[64][65];
  const int m = blockIdx.z;
  const float* base = (m < 16) ? Wq : (m < 32) ? Wk : Wv;
  const float scale = (m < 16) ? qscale : 1.0f;
  const float* src = base + (size_t)(m & 15) * 1024 * 64;
  unsigned short* dst = out + (size_t)m * 1024 * 64;
  const int r0 = blockIdx.y * 64;
  const int tx = threadIdx.x & 63, ty = threadIdx.x >> 6;
#pragma unroll
  for (int it = 0; it < 16; ++it) {
    const int i = ty + it * 4;
    T[i][tx] = src[(size_t)(r0 + i) * 64 + tx];
  }
  __syncthreads();
#pragma unroll
  for (int it = 0; it < 16; ++it) {
    const int jj = ty + it * 4;
    dst[(size_t)jj * 1024 + r0 + tx] = f2bf(T[tx][jj] * scale);
  }
}

// ---------------------------------------------------------------------------
// Wo transpose + fp32->bf16: out[c][r] = in[r][c]
// ---------------------------------------------------------------------------
__global__ __launch_bounds__(256)
void tconv_k(const float* __restrict__ in, unsigned short* __restrict__ out,
             int R, int C) {
  __shared__ float T[64][65];
  const int c0 = blockIdx.x * 64, r0 = blockIdx.y * 64;
  const int tx = threadIdx.x & 63, ty = threadIdx.x >> 6;
#pragma unroll
  for (int it = 0; it < 16; ++it) {
    const int i = ty + it * 4;
    T[i][tx] = in[(size_t)(r0 + i) * C + c0 + tx];
  }
  __syncthreads();
#pragma unroll
  for (int it = 0; it < 16; ++it) {
    const int jj = ty + it * 4;
    out[(size_t)(c0 + jj) * R + r0 + tx] = f2bf(T[tx][jj]);
  }
}

// ---------------------------------------------------------------------------
// Merged QKV projection: A[4096][1024] @ wqkvT[3072][1024]^T.
// 128x128 tile, BK=64, 4 waves, SINGLE-buffered 32KB LDS (m97 structure:
// stage -> sync -> compute -> sync; wave-level overlap across 4 blocks/CU
// hides the drain), T2 XOR-swizzle, 16x16x32 MFMA.
// col0 < 2048 -> q/k (TRANSPOSED acc via operand swap, ushort4 [bh][s][e]);
// else v (normal acc, ushort4 V^T [bh][e][s]).
// ---------------------------------------------------------------------------
__global__ __launch_bounds__(256)
void gemm_qkv(const unsigned short* __restrict__ A,
              const unsigned short* __restrict__ Bt,
              unsigned short* __restrict__ q_out,
              unsigned short* __restrict__ k_out,
              unsigned short* __restrict__ vt_out)
{
  __shared__ unsigned short As[128 * 64];
  __shared__ unsigned short Bs[128 * 64];

  const int K = 1024;
  const int tid = threadIdx.x;
  const int w = tid >> 6, lane = tid & 63;
  const int lo = lane & 15, hi = lane >> 4;
  const int wr = w >> 1, wc = w & 1;
  const int row0 = blockIdx.y * 128;
  const int col0 = blockIdx.x * 128;
  const bool isv = (col0 >= 2048);

  f32x4 acc[4][4] = {};

  const int srow = w * 32 + (lane >> 3);
  const int scol = ((lane & 7) ^ (lane >> 3)) * 8;
  const int swl  = (lo & 7) << 4;

  for (int t = 0; t < 16; ++t) {
    const int k0 = t * 64;
#pragma unroll
    for (int c = 0; c < 4; ++c) {
      const int rr = srow + c * 8;
      gld16(A  + (size_t)(row0 + rr) * K + (k0 + scol),
            (char*)As + (w * 4 + c) * 1024);
      gld16(Bt + (size_t)(col0 + rr) * K + (k0 + scol),
            (char*)Bs + (w * 4 + c) * 1024);
    }
    __syncthreads();
#pragma unroll
    for (int ks = 0; ks < 2; ++ks) {
      bf16x8 af[4], bfr[4];
#pragma unroll
      for (int i = 0; i < 4; ++i)
        af[i] = *(const bf16x8*)((const char*)As +
                 (wr * 64 + i * 16 + lo) * 128 + ((ks * 64 + hi * 16) ^ swl));
#pragma unroll
      for (int j = 0; j < 4; ++j)
        bfr[j] = *(const bf16x8*)((const char*)Bs +
                 (wc * 64 + j * 16 + lo) * 128 + ((ks * 64 + hi * 16) ^ swl));
      __builtin_amdgcn_s_setprio(1);
      if (isv) {
#pragma unroll
        for (int i = 0; i < 4; ++i)
#pragma unroll
          for (int j = 0; j < 4; ++j)
            acc[i][j] = __builtin_amdgcn_mfma_f32_16x16x32_bf16(af[i], bfr[j], acc[i][j], 0, 0, 0);
      } else {
#pragma unroll
        for (int i = 0; i < 4; ++i)
#pragma unroll
          for (int j = 0; j < 4; ++j)
            acc[i][j] = __builtin_amdgcn_mfma_f32_16x16x32_bf16(bfr[j], af[i], acc[i][j], 0, 0, 0);
      }
      __builtin_amdgcn_s_setprio(0);
    }
    __syncthreads();
  }

#pragma unroll
  for (int i = 0; i < 4; ++i) {
#pragma unroll
    for (int j = 0; j < 4; ++j) {
      if (isv) {
        // normal acc: lane holds 4 consecutive s at fixed e
        const int grow = row0 + wr * 64 + i * 16 + hi * 4;
        const int gcol = col0 + wc * 64 + j * 16 + lo;     // 2048..3071
        const int hd = (gcol >> 6) & 15, e = gcol & 63;
        const int bb2 = grow >> 11, s = grow & 2047;
        ushort4 pk;
        pk.x = f2bf(acc[i][j][0]); pk.y = f2bf(acc[i][j][1]);
        pk.z = f2bf(acc[i][j][2]); pk.w = f2bf(acc[i][j][3]);
        *(ushort4*)&vt_out[((size_t)(bb2 * Hh + hd) * HD + e) * Ss + s] = pk;
      } else {
        // transposed acc: lane holds 4 consecutive n at fixed row m
        const int m  = row0 + wr * 64 + i * 16 + lo;
        const int n0 = col0 + wc * 64 + j * 16 + hi * 4;
        const int p = n0 >> 10;
        const int hd = (n0 >> 6) & 15, e = n0 & 63;
        const int bb2 = m >> 11, s = m & 2047;
        unsigned short* dst = (p == 0) ? q_out : k_out;
        ushort4 pk;
        pk.x = f2bf(acc[i][j][0]); pk.y = f2bf(acc[i][j][1]);
        pk.z = f2bf(acc[i][j][2]); pk.w = f2bf(acc[i][j][3]);
        *(ushort4*)&dst[((size_t)(bb2 * Hh + hd) * Ss + s) * HD + e] = pk;
      }
    }
  }
}

// ---------------------------------------------------------------------------
// Out-projection GEMM: [4096x1024] @ woT[1024][1024]^T + bias, fp32 out.
// 64x128 tile (M-split for 512 blocks = 2/CU), 24KB single-buffered LDS,
// T2 swizzle, TRANSPOSED acc -> float4 stores.
// ---------------------------------------------------------------------------
__global__ __launch_bounds__(256)
void gemm_out(const unsigned short* __restrict__ A,
              const unsigned short* __restrict__ Bt,
              float* __restrict__ o_out,
              const float* __restrict__ bias)
{
  __shared__ unsigned short As[64 * 64];    //  8 KB
  __shared__ unsigned short Bs[128 * 64];   // 16 KB

  const int K = 1024, Ndim = 1024;
  const int tid = threadIdx.x;
  const int w = tid >> 6, lane = tid & 63;
  const int lo = lane & 15, hi = lane >> 4;
  const int wr = w >> 1, wc = w & 1;
  const int row0 = blockIdx.y * 64;
  const int col0 = blockIdx.x * 128;

  f32x4 acc[2][4] = {};

  const int sr   = lane >> 3;
  const int scol = ((lane & 7) ^ sr) * 8;
  const int swl  = (lo & 7) << 4;

  for (int t = 0; t < 16; ++t) {
    const int k0 = t * 64;
#pragma unroll
    for (int c = 0; c < 2; ++c)
      gld16(A + (size_t)(row0 + c * 32 + w * 8 + sr) * K + (k0 + scol),
            (char*)As + c * 4096 + w * 1024);
#pragma unroll
    for (int c = 0; c < 4; ++c)
      gld16(Bt + (size_t)(col0 + c * 32 + w * 8 + sr) * K + (k0 + scol),
            (char*)Bs + c * 4096 + w * 1024);
    __syncthreads();
#pragma unroll
    for (int ks = 0; ks < 2; ++ks) {
      bf16x8 af[2], bfr[4];
#pragma unroll
      for (int i = 0; i < 2; ++i)
        af[i] = *(const bf16x8*)((const char*)As +
                 (wr * 32 + i * 16 + lo) * 128 + ((ks * 64 + hi * 16) ^ swl));
#pragma unroll
      for (int j = 0; j < 4; ++j)
        bfr[j] = *(const bf16x8*)((const char*)Bs +
                 (wc * 64 + j * 16 + lo) * 128 + ((ks * 64 + hi * 16) ^ swl));
      __builtin_amdgcn_s_setprio(1);
#pragma unroll
      for (int i = 0; i < 2; ++i)
#pragma unroll
        for (int j = 0; j < 4; ++j)
          acc[i][j] = __builtin_amdgcn_mfma_f32_16x16x32_bf16(bfr[j], af[i], acc[i][j], 0, 0, 0);
      __builtin_amdgcn_s_setprio(0);
    }
    __syncthreads();
  }

#pragma unroll
  for (int i = 0; i < 2; ++i) {
#pragma unroll
    for (int j = 0; j < 4; ++j) {
      const int m  = row0 + wr * 32 + i * 16 + lo;
      const int n0 = col0 + wc * 64 + j * 16 + hi * 4;
      const float4 bv = *(const float4*)&bias[n0];
      float4 o;
      o.x = acc[i][j][0] + bv.x; o.y = acc[i][j][1] + bv.y;
      o.z = acc[i][j][2] + bv.z; o.w = acc[i][j][3] + bv.w;
      *(float4*)&o_out[(size_t)m * Ndim + n0] = o;
    }
  }
}

// ---------------------------------------------------------------------------
// Flash attention, causal, swapped-QK^T in-register-P, 4 waves x 16 q-rows.
// grid (B*H, S/64 reversed heavy-first), 256 thr. K rows staged through
// bit-perm perm(p)={p5,p3,p2,p4,p1,p0} so the swapped MFMA output (lane holds
// q=lane&15, kv slices in regs) is EXACTLY PV's A-fragment order: P stays in
// registers. Defer-max lane-local common path; rare rescale via xor16/32
// shfl + 16-lane redistribute. Row sums via MFMA-with-ones. Scores in log2
// domain (scale folded into Wq).
// ---------------------------------------------------------------------------
__global__ __launch_bounds__(256)
void attn_fwd(const unsigned short* __restrict__ qb,
              const unsigned short* __restrict__ kb,
              const unsigned short* __restrict__ vtb,
              unsigned short* __restrict__ ob)
{
  __shared__ unsigned short Ks[2][64 * 64];
  __shared__ unsigned short Vs[2][64 * 64];

  const int qt = 31 - blockIdx.y;        // heavy-first dispatch
  const int bh = blockIdx.x;
  const int bb2 = bh >> 4;
  const int hd = bh & 15;

  const unsigned short* Q  = qb  + (size_t)bh * Ss * HD;
  const unsigned short* Kg = kb  + (size_t)bh * Ss * HD;
  const unsigned short* Vt = vtb + (size_t)bh * HD * Ss;

  const int tid = threadIdx.x;
  const int w = tid >> 6, lane = tid & 63;
  const int lo = lane & 15, hi = lane >> 4;
  const int qrow0 = qt * 64 + w * 16;

  // staging: LDS row p = L*8 + sr (L = c*4+w), 8 lanes per row.
  const int sr   = lane >> 3;
  const int scol = ((lane & 7) ^ sr) * 8;   // pre-swizzled source col (elems)
  int prow[2];
#pragma unroll
  for (int c = 0; c < 2; ++c) {
    const int L = c * 4 + w;
    prow[c] = (L >> 2) * 32 + ((L & 1) * 2 + (sr >> 2)) * 8 + ((L >> 1) & 1) * 4 + (sr & 3);
  }

#define STAGE(bi, kv)                                                     \
  _Pragma("unroll")                                                       \
  for (int c = 0; c < 2; ++c) {                                           \
    const int L = c * 4 + w;                                              \
    gld16(Kg + (size_t)((kv) + prow[c]) * HD + scol,                      \
          (char*)&Ks[bi][0] + L * 1024);                                  \
    gld16(Vt + (size_t)(L * 8 + sr) * Ss + (kv) + scol,                   \
          (char*)&Vs[bi][0] + L * 1024);                                  \
  }

  const int swl = (lo & 7) << 4;   // read-side XOR

  bf16x8 vones;
#pragma unroll
  for (int j = 0; j < 8; ++j) vones[j] = (__bf16)1.0f;

  bf16x8 qf[2];
#pragma unroll
  for (int ks = 0; ks < 2; ++ks)
    qf[ks] = *(const bf16x8*)&Q[(size_t)(qrow0 + lo) * HD + ks * 32 + hi * 8];

  f32x4 oacc[4] = {};
  float m2s = -INFINITY;   // running max, sacc domain (q = qrow0+lo)
  float l2[4];             // running denom, oacc domain (q = qrow0+hi*4+r)
#pragma unroll
  for (int r = 0; r < 4; ++r) l2[r] = 0.f;

  const int ntiles = qt + 1;

  STAGE(0, 0);
  __syncthreads();

  int cur = 0;
  for (int t = 0; t < ntiles; ++t) {
    if (t + 1 < ntiles) { STAGE(cur ^ 1, (t + 1) * 64); }

    // S^T = K Q^T (swapped): lane holds q = qrow0+lo,
    // reg (nj,r) holds kv = (nj>>1)*32 + (nj&1)*4 + hi*8 + r  (via perm)
    f32x4 sacc[4] = {};
    __builtin_amdgcn_s_setprio(1);
#pragma unroll
    for (int ks = 0; ks < 2; ++ks) {
      bf16x8 kf[4];
#pragma unroll
      for (int nj = 0; nj < 4; ++nj)
        kf[nj] = *(const bf16x8*)((const char*)&Ks[cur][0] +
                 (nj * 16 + lo) * 128 + ((ks * 64 + hi * 16) ^ swl));
#pragma unroll
      for (int nj = 0; nj < 4; ++nj)
        sacc[nj] = __builtin_amdgcn_mfma_f32_16x16x32_bf16(kf[nj], qf[ks], sacc[nj], 0, 0, 0);
    }
    __builtin_amdgcn_s_setprio(0);

    // causal mask (diagonal tile only); indices tile-local
    if (t == qt) {
      const int qr = w * 16 + lo;
#pragma unroll
      for (int nj = 0; nj < 4; ++nj) {
        const int kb0 = (nj >> 1) * 32 + (nj & 1) * 4 + hi * 8;
#pragma unroll
        for (int r = 0; r < 4; ++r)
          if (kb0 + r > qr) sacc[nj][r] = -INFINITY;
      }
    }

    // lane-local max + defer-max test (no cross-lane in common path)
    float a0 = fmaxf(fmaxf(sacc[0][0], sacc[0][1]), fmaxf(sacc[0][2], sacc[0][3]));
    float a1 = fmaxf(fmaxf(sacc[1][0], sacc[1][1]), fmaxf(sacc[1][2], sacc[1][3]));
    float a2 = fmaxf(fmaxf(sacc[2][0], sacc[2][1]), fmaxf(sacc[2][2], sacc[2][3]));
    float a3 = fmaxf(fmaxf(sacc[3][0], sacc[3][1]), fmaxf(sacc[3][2], sacc[3][3]));
    const float lmax = fmaxf(fmaxf(a0, a1), fmaxf(a2, a3));
    if (!__all(lmax - m2s <= 8.0f)) {
      float rm = lmax;
      rm = fmaxf(rm, __shfl_xor(rm, 16, 64));
      rm = fmaxf(rm, __shfl_xor(rm, 32, 64));
      const float mn = fmaxf(m2s, rm);
      const float rcs = __builtin_amdgcn_exp2f(m2s - mn);
      m2s = mn;
#pragma unroll
      for (int r = 0; r < 4; ++r) {
        const float rc = __shfl(rcs, hi * 4 + r, 64);
        l2[r] *= rc;
#pragma unroll
        for (int nj = 0; nj < 4; ++nj)
          oacc[nj][r] *= rc;
      }
    }

    // P = exp2(S - m) packed straight into PV A-fragments (in registers)
    bf16x8 pa[2];
#pragma unroll
    for (int ks = 0; ks < 2; ++ks)
#pragma unroll
      for (int j = 0; j < 4; ++j) {
        pa[ks][j]     = (__bf16)__builtin_amdgcn_exp2f(sacc[2 * ks][j]     - m2s);
        pa[ks][4 + j] = (__bf16)__builtin_amdgcn_exp2f(sacc[2 * ks + 1][j] - m2s);
      }

    // O += P V ; row sums via MFMA-with-ones
    f32x4 osum = {};
    __builtin_amdgcn_s_setprio(1);
#pragma unroll
    for (int ks = 0; ks < 2; ++ks) {
      bf16x8 vf[4];
#pragma unroll
      for (int nj = 0; nj < 4; ++nj)
        vf[nj] = *(const bf16x8*)((const char*)&Vs[cur][0] +
                 (nj * 16 + lo) * 128 + ((ks * 64 + hi * 16) ^ swl));
#pragma unroll
      for (int nj = 0; nj < 4; ++nj)
        oacc[nj] = __builtin_amdgcn_mfma_f32_16x16x32_bf16(pa[ks], vf[nj], oacc[nj], 0, 0, 0);
      osum = __builtin_amdgcn_mfma_f32_16x16x32_bf16(pa[ks], vones, osum, 0, 0, 0);
    }
    __builtin_amdgcn_s_setprio(0);
#pragma unroll
    for (int r = 0; r < 4; ++r)
      l2[r] += osum[r];

    __syncthreads();
    cur ^= 1;
  }
#undef STAGE

  // epilogue: ob[b][s][h*64+e] bf16
#pragma unroll
  for (int r = 0; r < 4; ++r) {
    const int s = qrow0 + hi * 4 + r;
    const float il = 1.0f / l2[r];
    const size_t base = ((size_t)bb2 * Ss + s) * Dd + hd * HD;
#pragma unroll
    for (int nj = 0; nj < 4; ++nj)
      ob[base + nj * 16 + lo] = f2bf(oacc[nj][r] * il);
  }
}

// ---------------------------------------------------------------------------
extern "C" void kernel_launch(void* const* d_in, const int* in_sizes, int n_in,
                              void* d_out, int out_size, void* d_ws, size_t ws_size,
                              hipStream_t stream)
{
  const float* x  = (const float*)d_in[0];
  const float* Wq = (const float*)d_in[1];
  const float* Wk = (const float*)d_in[2];
  const float* Wv = (const float*)d_in[3];
  const float* Wo = (const float*)d_in[4];
  const float* bo = (const float*)d_in[5];
  float* out = (float*)d_out;

  char* ws = (char*)d_ws;
  unsigned short* xb    = (unsigned short*)(ws);              //  8,388,608 B
  unsigned short* wqkvT = (unsigned short*)(ws + 8388608);    //  6,291,456 B
  unsigned short* woT   = (unsigned short*)(ws + 14680064);   //  2,097,152 B
  unsigned short* qb    = (unsigned short*)(ws + 16777216);   //  8,388,608 B
  unsigned short* kb    = (unsigned short*)(ws + 25165824);   //  8,388,608 B
  unsigned short* vtb   = (unsigned short*)(ws + 33554432);   //  8,388,608 B
  unsigned short* ob    = (unsigned short*)(ws + 41943040);   //  8,388,608 B (end 48 MiB)

  pack_x_k<<<4096, 256, 0, stream>>>((const float4*)x, xb, 1048576);
  // Wq carries 1/sqrt(HD) * log2(e) so attention scores land in log2 domain
  tconv_qkv<<<dim3(1, 16, 48), 256, 0, stream>>>(Wq, Wk, Wv, wqkvT,
                                                 0.18033688011112042f);
  tconv_k<<<dim3(16, 16, 1), 256, 0, stream>>>(Wo, woT, 1024, 1024);

  // merged QKV projection: [4096x1024] @ [1024x3072] (single-buffered, 4 blk/CU)
  gemm_qkv<<<dim3(24, 32), 256, 0, stream>>>(xb, wqkvT, qb, kb, vtb);
  // attention (4 waves x 16 q-rows per 64-row q-tile; in-register P)
  attn_fwd<<<dim3(32, 32), 256, 0, stream>>>(qb, kb, vtb, ob);
  // out-proj: [4096x1024] @ [1024x1024] + bo (64x128 tile, 512 blocks)
  gemm_out<<<dim3(8, 64), 256, 0, stream>>>(ob, woT, out, bo);
}